// Round 4
// baseline (349.994 us; speedup 1.0000x reference)
//
#include <hip/hip_runtime.h>

#define NB  2
#define NH  12
#define NQ  2048
#define NKV 2048
#define DH  64
#define KVB 64
#define QTB 32     // q-rows per block

typedef __attribute__((ext_vector_type(8))) short bf16x8;
typedef __attribute__((ext_vector_type(4))) float f32x4;

__device__ __forceinline__ unsigned short f2bf(float f) {
    unsigned int u = __float_as_uint(f);
    u += 0x7FFFu + ((u >> 16) & 1u);          // round-to-nearest-even
    return (unsigned short)(u >> 16);
}
__device__ __forceinline__ float bf2f(unsigned short h) {
    return __uint_as_float((unsigned int)h << 16);
}

// LDS arena (bytes):
//   [0,     4160)  bias_s : bf16[2080]              (whole kernel)
//   [4160, 12864)  Ks     : u16[64][68]   (kv loop) | merge: mO f32[2][16][68] = 8704 B
//   [12864,21568)  Vs     : u16[64][68]   (kv loop) | merge: mML f32[64]       = 256 B
//   [21568,26176)  Ps     : u16[4][16][36]
#define ARENA_BYTES 26176

__global__ __launch_bounds__(256, 4)
void attn_fwd(const float* __restrict__ Q, const float* __restrict__ K,
              const float* __restrict__ V, const float* __restrict__ M,
              const float* __restrict__ Bias, float* __restrict__ O)
{
    const int tid  = threadIdx.x;
    const int w    = tid >> 6;      // wave 0..3
    const int wq   = w >> 1;        // q-sub-tile: rows [wq*16, wq*16+16)
    const int wk   = w & 1;         // kv-half: [wk*32, wk*32+32) of each 64-tile
    const int lane = tid & 63;
    const int l16  = lane & 15;
    const int g    = lane >> 4;

    const int qt = blockIdx.x & 63;            // 64 q-tiles of 32
    const int h  = (blockIdx.x >> 6) % NH;
    const int b  = blockIdx.x / (64 * NH);
    const int q0 = qt * QTB;

    __shared__ __align__(16) char arena[ARENA_BYTES];
    unsigned short* bias_s           = (unsigned short*)arena;
    unsigned short (*Ks)[68]         = (unsigned short(*)[68])(arena + 4160);
    unsigned short (*Vs)[68]         = (unsigned short(*)[68])(arena + 12864);
    unsigned short (*Ps)[16][36]     = (unsigned short(*)[16][36])(arena + 21568);

    // ---- stage bias band: pos = q-k+2048, q in [q0,q0+32), k in [0,2048)
    //      band index i -> Bias[(q0+1+i)*NH + h], i in [0, 2080)
    for (int i = tid; i < 2080; i += 256)
        bias_s[i] = f2bf(Bias[(size_t)(q0 + 1 + i) * NH + h]);

    // ---- Q fragments (A-frag: row = l16, k = g*8+j), d split into two K=32 chunks
    const float* qptr = Q + (((size_t)b * NH + h) * NQ + q0 + wq * 16 + l16) * DH;
    bf16x8 qa[2];
#pragma unroll
    for (int dc = 0; dc < 2; ++dc) {
        const float4 f0 = *(const float4*)(qptr + dc * 32 + g * 8);
        const float4 f1 = *(const float4*)(qptr + dc * 32 + g * 8 + 4);
        qa[dc][0] = (short)f2bf(f0.x); qa[dc][1] = (short)f2bf(f0.y);
        qa[dc][2] = (short)f2bf(f0.z); qa[dc][3] = (short)f2bf(f0.w);
        qa[dc][4] = (short)f2bf(f1.x); qa[dc][5] = (short)f2bf(f1.y);
        qa[dc][6] = (short)f2bf(f1.z); qa[dc][7] = (short)f2bf(f1.w);
    }

    f32x4 o[4];
#pragma unroll
    for (int nt = 0; nt < 4; ++nt) { o[nt][0]=0.f; o[nt][1]=0.f; o[nt][2]=0.f; o[nt][3]=0.f; }
    float m_r[4] = {-1e30f, -1e30f, -1e30f, -1e30f};
    float l_r[4] = {0.f, 0.f, 0.f, 0.f};

    const float* kbase = K + ((size_t)b * NH + h) * NKV * DH;
    const float* vbase = V + ((size_t)b * NH + h) * NKV * DH;
    // mask base for this wave: row (q0 + wq*16 + g*4), col (wk*32 + l16)
    const float* mbase = M + (size_t)b * NQ * NKV
                           + (size_t)(q0 + wq * 16 + g * 4) * NKV + wk * 32 + l16;

    // staging mapping: 64x64 tile, 256 threads: rows i*16+r0, cols c0..c0+3
    const int r0 = tid >> 4, c0 = (tid & 15) * 4;

    // ---- prologue: issue tile-0 loads into registers
    float4 kr[4], vr[4];
    float  mr[4][2];
#pragma unroll
    for (int i = 0; i < 4; ++i)
        kr[i] = *(const float4*)(kbase + (size_t)(i * 16 + r0) * DH + c0);
#pragma unroll
    for (int i = 0; i < 4; ++i)
        vr[i] = *(const float4*)(vbase + (size_t)(i * 16 + r0) * DH + c0);
#pragma unroll
    for (int r = 0; r < 4; ++r)
#pragma unroll
        for (int nt = 0; nt < 2; ++nt) mr[r][nt] = mbase[r * NKV + nt * 16];

    for (int t = 0; t < NKV / KVB; ++t) {
        const int kv0 = t * KVB;
        const int kvn = ((t + 1) & (NKV / KVB - 1)) * KVB;  // wraps on last iter

        __syncthreads();   // all waves done reading previous LDS tile
        // ---- staged registers -> LDS (bf16)
#pragma unroll
        for (int i = 0; i < 4; ++i) {
            unsigned short* dst = &Ks[i * 16 + r0][c0];
            dst[0] = f2bf(kr[i].x); dst[1] = f2bf(kr[i].y);
            dst[2] = f2bf(kr[i].z); dst[3] = f2bf(kr[i].w);
        }
#pragma unroll
        for (int i = 0; i < 4; ++i) {
            const int rr = i * 16 + r0;
            Vs[c0 + 0][rr] = f2bf(vr[i].x); Vs[c0 + 1][rr] = f2bf(vr[i].y);
            Vs[c0 + 2][rr] = f2bf(vr[i].z); Vs[c0 + 3][rr] = f2bf(vr[i].w);
        }
        // ---- issue next-tile K/V loads (hide under compute)
#pragma unroll
        for (int i = 0; i < 4; ++i)
            kr[i] = *(const float4*)(kbase + (size_t)(kvn + i * 16 + r0) * DH + c0);
#pragma unroll
        for (int i = 0; i < 4; ++i)
            vr[i] = *(const float4*)(vbase + (size_t)(kvn + i * 16 + r0) * DH + c0);
        __syncthreads();   // LDS tile ready

        // ---- S = Q K^T for this wave's 16q x 32kv slice
        f32x4 s[2];
#pragma unroll
        for (int nt = 0; nt < 2; ++nt) {
            f32x4 acc; acc[0]=0.f; acc[1]=0.f; acc[2]=0.f; acc[3]=0.f;
            const int kvrow = wk * 32 + nt * 16 + l16;
            const bf16x8 kb0 = *(const bf16x8*)(&Ks[kvrow][g * 8]);
            const bf16x8 kb1 = *(const bf16x8*)(&Ks[kvrow][32 + g * 8]);
            acc = __builtin_amdgcn_mfma_f32_16x16x32_bf16(qa[0], kb0, acc, 0, 0, 0);
            acc = __builtin_amdgcn_mfma_f32_16x16x32_bf16(qa[1], kb1, acc, 0, 0, 0);
            s[nt] = acc;
        }

        // ---- scale + bias + mask, online softmax (local row = wq*16 + g*4 + r)
#pragma unroll
        for (int r = 0; r < 4; ++r) {
            const int qr = wq * 16 + g * 4 + r;
#pragma unroll
            for (int nt = 0; nt < 2; ++nt) {
                const int kk = kv0 + wk * 32 + nt * 16 + l16;
                float x = s[nt][r] * 0.125f + mr[r][nt];
                x += bf2f(bias_s[qr - kk + 2047]);
                s[nt][r] = x;
            }
            float mx = fmaxf(s[0][r], s[1][r]);
            mx = fmaxf(mx, __shfl_xor(mx, 1));
            mx = fmaxf(mx, __shfl_xor(mx, 2));
            mx = fmaxf(mx, __shfl_xor(mx, 4));
            mx = fmaxf(mx, __shfl_xor(mx, 8));
            const float mo = m_r[r];
            const float mn = fmaxf(mo, mx);
            m_r[r] = mn;
            const float alpha = __expf(mo - mn);
            const float p0 = __expf(s[0][r] - mn);
            const float p1 = __expf(s[1][r] - mn);
            float rs = p0 + p1;
            rs += __shfl_xor(rs, 1);
            rs += __shfl_xor(rs, 2);
            rs += __shfl_xor(rs, 4);
            rs += __shfl_xor(rs, 8);
            l_r[r] = l_r[r] * alpha + rs;
#pragma unroll
            for (int nt = 0; nt < 4; ++nt) o[nt][r] *= alpha;
            Ps[w][g * 4 + r][l16]      = f2bf(p0);
            Ps[w][g * 4 + r][16 + l16] = f2bf(p1);
        }

        // ---- issue next-tile mask loads
#pragma unroll
        for (int r = 0; r < 4; ++r)
#pragma unroll
            for (int nt = 0; nt < 2; ++nt) mr[r][nt] = mbase[r * NKV + kvn + nt * 16];

        // ---- PV: A = P (16x32 slice), B^T = V^T rows at kv = wk*32 + g*8
        const bf16x8 pa = *(const bf16x8*)(&Ps[w][l16][g * 8]);
#pragma unroll
        for (int nt = 0; nt < 4; ++nt) {
            const bf16x8 vb = *(const bf16x8*)(&Vs[nt * 16 + l16][wk * 32 + g * 8]);
            o[nt] = __builtin_amdgcn_mfma_f32_16x16x32_bf16(pa, vb, o[nt], 0, 0, 0);
        }
    }

    // ==== merge the two kv-halves (wk=0 <- wk=1) through LDS ====
    __syncthreads();   // kv loop done; Ks/Vs regions reusable
    float (*mO)[16][68] = (float(*)[16][68])(arena + 4160);   // 8704 B
    float* mML          = (float*)(arena + 12864);            // m[32] | l[32]

    if (wk == 1) {
#pragma unroll
        for (int r = 0; r < 4; ++r) {
#pragma unroll
            for (int nt = 0; nt < 4; ++nt)
                mO[wq][g * 4 + r][nt * 16 + l16] = o[nt][r];
            if (l16 == 0) {
                mML[wq * 16 + g * 4 + r]      = m_r[r];
                mML[32 + wq * 16 + g * 4 + r] = l_r[r];
            }
        }
    }
    __syncthreads();
    if (wk == 0) {
        float* obase = O + (((size_t)b * NH + h) * NQ + q0 + wq * 16) * DH;
#pragma unroll
        for (int r = 0; r < 4; ++r) {
            const int row = g * 4 + r;
            const float m1 = mML[wq * 16 + row];
            const float l1 = mML[32 + wq * 16 + row];
            const float mn = fmaxf(m_r[r], m1);
            const float a0 = __expf(m_r[r] - mn);
            const float a1 = __expf(m1 - mn);
            const float inv = 1.f / (l_r[r] * a0 + l1 * a1);
#pragma unroll
            for (int nt = 0; nt < 4; ++nt)
                obase[(size_t)row * DH + nt * 16 + l16] =
                    (o[nt][r] * a0 + mO[wq][row][nt * 16 + l16] * a1) * inv;
        }
    }
}

extern "C" void kernel_launch(void* const* d_in, const int* in_sizes, int n_in,
                              void* d_out, int out_size, void* d_ws, size_t ws_size,
                              hipStream_t stream) {
    const float* Q    = (const float*)d_in[0];
    const float* K    = (const float*)d_in[1];
    const float* V    = (const float*)d_in[2];
    const float* M    = (const float*)d_in[3];
    const float* Bias = (const float*)d_in[4];
    float* O = (float*)d_out;

    dim3 grid(NB * NH * (NQ / QTB));   // 1536 blocks = 6/CU, 4 waves each
    dim3 block(256);
    attn_fwd<<<grid, block, 0, stream>>>(Q, K, V, M, Bias, O);
}

// Round 5
// 278.294 us; speedup vs baseline: 1.2576x; 1.2576x over previous
//
#include <hip/hip_runtime.h>

#define NB  2
#define NH  12
#define NQ  2048
#define NKV 2048
#define DH  64
#define BH  (NB * NH)

typedef __attribute__((ext_vector_type(8))) short bf16x8;
typedef __attribute__((ext_vector_type(4))) float f32x4;

// workspace layout (bytes)
#define WS_KB   0u
#define WS_VT   6291456u
#define WS_OP   12582912u
#define WS_ML   37748736u
#define WS_NEED 38535168u
#define OPHALF  ((size_t)BH * NQ * DH)
#define MLHALF  ((size_t)BH * NQ)

__device__ __forceinline__ unsigned short f2bf(float f) {
    unsigned int u = __float_as_uint(f);
    u += 0x7FFFu + ((u >> 16) & 1u);
    return (unsigned short)(u >> 16);
}
__device__ __forceinline__ float bf2f(unsigned short h) {
    return __uint_as_float((unsigned int)h << 16);
}

// ============ pass 1: K -> bf16 copy, V -> bf16 transpose ============
__global__ __launch_bounds__(256)
void conv_kv(const float* __restrict__ K, const float* __restrict__ V,
             unsigned short* __restrict__ Kb, unsigned short* __restrict__ Vt)
{
    const int tid = threadIdx.x;
    const int kvt = blockIdx.x & 31;
    const int bh  = blockIdx.x >> 5;
    const int kv0 = kvt * 64;

    const float* ksrc = K + ((size_t)bh * NKV + kv0) * DH;
    const float* vsrc = V + ((size_t)bh * NKV + kv0) * DH;
    unsigned short* kdst = Kb + ((size_t)bh * NKV + kv0) * DH;
    unsigned short* vdst = Vt + (size_t)bh * DH * NKV + kv0;

    __shared__ float Ts[64][65];

#pragma unroll
    for (int p = 0; p < 2; ++p) {
        const int ch = p * 256 + tid;
        const int row = ch >> 3, c8 = (ch & 7) * 8;
        const float4 f0 = *(const float4*)(ksrc + (size_t)row * DH + c8);
        const float4 f1 = *(const float4*)(ksrc + (size_t)row * DH + c8 + 4);
        bf16x8 o;
        o[0] = (short)f2bf(f0.x); o[1] = (short)f2bf(f0.y);
        o[2] = (short)f2bf(f0.z); o[3] = (short)f2bf(f0.w);
        o[4] = (short)f2bf(f1.x); o[5] = (short)f2bf(f1.y);
        o[6] = (short)f2bf(f1.z); o[7] = (short)f2bf(f1.w);
        *(bf16x8*)(kdst + (size_t)row * DH + c8) = o;
    }
#pragma unroll
    for (int p = 0; p < 4; ++p) {
        const int fi = p * 1024 + tid * 4;
        const int row = fi >> 6, col = fi & 63;
        const float4 f = *(const float4*)(vsrc + (size_t)row * DH + col);
        Ts[row][col] = f.x; Ts[row][col + 1] = f.y;
        Ts[row][col + 2] = f.z; Ts[row][col + 3] = f.w;
    }
    __syncthreads();
#pragma unroll
    for (int p = 0; p < 2; ++p) {
        const int ch = p * 256 + tid;
        const int d = ch >> 3, c8 = (ch & 7) * 8;
        bf16x8 o;
#pragma unroll
        for (int j = 0; j < 8; ++j) o[j] = (short)f2bf(Ts[c8 + j][d]);
        *(bf16x8*)(vdst + (size_t)d * NKV + c8) = o;
    }
}

// ============ pass 2: flash attention over one kv-half ============
__global__ __launch_bounds__(256, 6)
void attn_split(const unsigned short* __restrict__ Kb, const unsigned short* __restrict__ Vt,
                const float* __restrict__ Q, const float* __restrict__ M,
                const float* __restrict__ Bias, float* __restrict__ Op,
                float* __restrict__ Ml)
{
    const int tid  = threadIdx.x;
    const int wv   = tid >> 6;
    const int lane = tid & 63;
    const int l16  = lane & 15;
    const int g    = lane >> 4;

    const int half = blockIdx.x & 1;
    const int qt   = (blockIdx.x >> 1) & 31;
    const int bh   = blockIdx.x >> 6;
    const int h    = bh % NH;
    const int b    = bh / NH;
    const int q0   = qt * 64;
    const int kv_lo = half * (NKV / 2);

    __shared__ unsigned short bias_s[1088];
    __shared__ unsigned short Ks[64][72];
    __shared__ unsigned short Vs[64][72];
    __shared__ unsigned short Ps[4][16][40];   // 16q x 32k chunk per wave

    const int minpos = q0 - kv_lo + 1025;
    for (int i = tid; i < 1088; i += 256)
        bias_s[i] = f2bf(Bias[(size_t)(minpos + i) * NH + h]);

    const float* qptr = Q + ((size_t)bh * NQ + q0 + wv * 16 + l16) * DH;
    bf16x8 qa[2];
#pragma unroll
    for (int dc = 0; dc < 2; ++dc) {
        const float4 f0 = *(const float4*)(qptr + dc * 32 + g * 8);
        const float4 f1 = *(const float4*)(qptr + dc * 32 + g * 8 + 4);
        qa[dc][0] = (short)f2bf(f0.x); qa[dc][1] = (short)f2bf(f0.y);
        qa[dc][2] = (short)f2bf(f0.z); qa[dc][3] = (short)f2bf(f0.w);
        qa[dc][4] = (short)f2bf(f1.x); qa[dc][5] = (short)f2bf(f1.y);
        qa[dc][6] = (short)f2bf(f1.z); qa[dc][7] = (short)f2bf(f1.w);
    }

    f32x4 o[4];
#pragma unroll
    for (int nt = 0; nt < 4; ++nt) { o[nt][0]=0.f; o[nt][1]=0.f; o[nt][2]=0.f; o[nt][3]=0.f; }
    float m_r[4] = {-1e30f, -1e30f, -1e30f, -1e30f};
    float l_r[4] = {0.f, 0.f, 0.f, 0.f};

    const unsigned short* kbB = Kb + ((size_t)bh * NKV + kv_lo) * DH;
    const unsigned short* vtB = Vt + (size_t)bh * DH * NKV + kv_lo;
    const float* mbase = M + (size_t)b * NQ * NKV
                           + (size_t)(q0 + wv * 16 + g * 4) * NKV + kv_lo + l16;

    const int srow = tid >> 3, sc8 = (tid & 7) * 8;

    bf16x8 krB[2], vrB[2];
    float  mr[4][4];
#pragma unroll
    for (int p = 0; p < 2; ++p) {
        krB[p] = *(const bf16x8*)(kbB + (size_t)(p * 32 + srow) * DH + sc8);
        vrB[p] = *(const bf16x8*)(vtB + (size_t)(p * 32 + srow) * NKV + sc8);
    }
#pragma unroll
    for (int r = 0; r < 4; ++r)
#pragma unroll
        for (int nt = 0; nt < 4; ++nt) mr[r][nt] = mbase[(size_t)r * NKV + nt * 16];

    for (int tl = 0; tl < 16; ++tl) {
        const int kvl0 = tl * 64;
        const int tn   = ((tl + 1) & 15) * 64;

        __syncthreads();
#pragma unroll
        for (int p = 0; p < 2; ++p)
            *(bf16x8*)(&Ks[p * 32 + srow][sc8]) = krB[p];
#pragma unroll
        for (int p = 0; p < 2; ++p)
            *(bf16x8*)(&Vs[p * 32 + srow][sc8]) = vrB[p];
#pragma unroll
        for (int p = 0; p < 2; ++p) {
            krB[p] = *(const bf16x8*)(kbB + (size_t)(tn + p * 32 + srow) * DH + sc8);
            vrB[p] = *(const bf16x8*)(vtB + (size_t)(p * 32 + srow) * NKV + tn + sc8);
        }
        __syncthreads();

        f32x4 s[4];
#pragma unroll
        for (int nt = 0; nt < 4; ++nt) {
            f32x4 acc; acc[0]=0.f; acc[1]=0.f; acc[2]=0.f; acc[3]=0.f;
            const bf16x8 kb0 = *(const bf16x8*)(&Ks[nt * 16 + l16][g * 8]);
            const bf16x8 kb1 = *(const bf16x8*)(&Ks[nt * 16 + l16][32 + g * 8]);
            acc = __builtin_amdgcn_mfma_f32_16x16x32_bf16(qa[0], kb0, acc, 0, 0, 0);
            acc = __builtin_amdgcn_mfma_f32_16x16x32_bf16(qa[1], kb1, acc, 0, 0, 0);
            s[nt] = acc;
        }

#pragma unroll
        for (int r = 0; r < 4; ++r) {
            const int qr = wv * 16 + g * 4 + r;
#pragma unroll
            for (int nt = 0; nt < 4; ++nt) {
                const int kk = kvl0 + nt * 16 + l16;
                float x = s[nt][r] * 0.125f + mr[r][nt];
                x += bf2f(bias_s[qr - kk + 1023]);
                s[nt][r] = x;
            }
            float mx = fmaxf(fmaxf(s[0][r], s[1][r]), fmaxf(s[2][r], s[3][r]));
            mx = fmaxf(mx, __shfl_xor(mx, 1));
            mx = fmaxf(mx, __shfl_xor(mx, 2));
            mx = fmaxf(mx, __shfl_xor(mx, 4));
            mx = fmaxf(mx, __shfl_xor(mx, 8));
            const float mo = m_r[r];
            const float mn = fmaxf(mo, mx);
            m_r[r] = mn;
            const float alpha = __expf(mo - mn);
            float p0 = __expf(s[0][r] - mn), p1 = __expf(s[1][r] - mn);
            float p2 = __expf(s[2][r] - mn), p3 = __expf(s[3][r] - mn);
            float rs = (p0 + p1) + (p2 + p3);
            rs += __shfl_xor(rs, 1);
            rs += __shfl_xor(rs, 2);
            rs += __shfl_xor(rs, 4);
            rs += __shfl_xor(rs, 8);
            l_r[r] = l_r[r] * alpha + rs;
#pragma unroll
            for (int nt = 0; nt < 4; ++nt) o[nt][r] *= alpha;
            // pack P^T for PV: s[0],s[1] -> cols [0,32); s[2],s[3] via second pass
            Ps[wv][g * 4 + r][l16]      = f2bf(p0);
            Ps[wv][g * 4 + r][16 + l16] = f2bf(p1);
            s[2][r] = p2; s[3][r] = p3;    // stash exp'd values for kc=1 pass
        }

        // PV pass kc=0 (kv local [0,32))
        {
            const bf16x8 pa = *(const bf16x8*)(&Ps[wv][l16][g * 8]);
#pragma unroll
            for (int nt = 0; nt < 4; ++nt) {
                const bf16x8 vb = *(const bf16x8*)(&Vs[nt * 16 + l16][g * 8]);
                o[nt] = __builtin_amdgcn_mfma_f32_16x16x32_bf16(pa, vb, o[nt], 0, 0, 0);
            }
        }
        // write second-half P (in-wave ordering makes this safe)
#pragma unroll
        for (int r = 0; r < 4; ++r) {
            Ps[wv][g * 4 + r][l16]      = f2bf(s[2][r]);
            Ps[wv][g * 4 + r][16 + l16] = f2bf(s[3][r]);
        }
        // prefetch next-tile mask
#pragma unroll
        for (int r = 0; r < 4; ++r)
#pragma unroll
            for (int nt = 0; nt < 4; ++nt) mr[r][nt] = mbase[(size_t)r * NKV + tn + nt * 16];
        // PV pass kc=1 (kv local [32,64))
        {
            const bf16x8 pa = *(const bf16x8*)(&Ps[wv][l16][g * 8]);
#pragma unroll
            for (int nt = 0; nt < 4; ++nt) {
                const bf16x8 vb = *(const bf16x8*)(&Vs[nt * 16 + l16][32 + g * 8]);
                o[nt] = __builtin_amdgcn_mfma_f32_16x16x32_bf16(pa, vb, o[nt], 0, 0, 0);
            }
        }
    }

    // partial outputs (unnormalized) + (m, l)
    float* opb = Op + half * OPHALF + ((size_t)bh * NQ + q0 + wv * 16) * DH;
#pragma unroll
    for (int r = 0; r < 4; ++r) {
        const int row = g * 4 + r;
#pragma unroll
        for (int nt = 0; nt < 4; ++nt)
            opb[(size_t)row * DH + nt * 16 + l16] = o[nt][r];
        if (l16 == 0) {
            const size_t mi = half * MLHALF + (size_t)bh * NQ + q0 + wv * 16 + row;
            Ml[mi * 2]     = m_r[r];
            Ml[mi * 2 + 1] = l_r[r];
        }
    }
}

// ============ pass 3: merge the two halves ============
__global__ __launch_bounds__(256)
void attn_merge(const float* __restrict__ Op, const float* __restrict__ Ml,
                float* __restrict__ O)
{
    const int gi  = blockIdx.x * 256 + threadIdx.x;   // one float4 each
    const int row = gi >> 4;
    const int d4  = (gi & 15) * 4;

    const float m0 = Ml[(size_t)row * 2];
    const float l0 = Ml[(size_t)row * 2 + 1];
    const float m1 = Ml[(MLHALF + row) * 2];
    const float l1 = Ml[(MLHALF + row) * 2 + 1];
    const float mm = fmaxf(m0, m1);
    const float a0 = __expf(m0 - mm);
    const float a1 = __expf(m1 - mm);
    const float inv = 1.f / (l0 * a0 + l1 * a1);

    const float4 x0 = *(const float4*)(Op + (size_t)row * DH + d4);
    const float4 x1 = *(const float4*)(Op + OPHALF + (size_t)row * DH + d4);
    float4 y;
    y.x = (x0.x * a0 + x1.x * a1) * inv;
    y.y = (x0.y * a0 + x1.y * a1) * inv;
    y.z = (x0.z * a0 + x1.z * a1) * inv;
    y.w = (x0.w * a0 + x1.w * a1) * inv;
    *(float4*)(O + (size_t)row * DH + d4) = y;
}

// ============ fallback (R2 kernel, known-good) ============
__global__ __launch_bounds__(256, 3)
void attn_full(const float* __restrict__ Q, const float* __restrict__ K,
               const float* __restrict__ V, const float* __restrict__ M,
               const float* __restrict__ Bias, float* __restrict__ O)
{
    const int tid  = threadIdx.x;
    const int wv   = tid >> 6;
    const int lane = tid & 63;
    const int l16  = lane & 15;
    const int g    = lane >> 4;

    const int qt = blockIdx.x & 31;
    const int h  = (blockIdx.x >> 5) % NH;
    const int b  = blockIdx.x / (32 * NH);
    const int q0 = qt * 64;

    __shared__ float bias_s[2112];
    __shared__ unsigned short Ks[64][72];
    __shared__ unsigned short Vs[64][72];
    __shared__ unsigned short Ps[4][16][72];

    for (int i = tid; i < 2112; i += 256)
        bias_s[i] = Bias[(size_t)(q0 + 1 + i) * NH + h];

    const float* qptr = Q + (((size_t)b * NH + h) * NQ + q0 + wv * 16 + l16) * DH;
    bf16x8 qa[2];
#pragma unroll
    for (int dc = 0; dc < 2; ++dc) {
        const float4 f0 = *(const float4*)(qptr + dc * 32 + g * 8);
        const float4 f1 = *(const float4*)(qptr + dc * 32 + g * 8 + 4);
        qa[dc][0] = (short)f2bf(f0.x); qa[dc][1] = (short)f2bf(f0.y);
        qa[dc][2] = (short)f2bf(f0.z); qa[dc][3] = (short)f2bf(f0.w);
        qa[dc][4] = (short)f2bf(f1.x); qa[dc][5] = (short)f2bf(f1.y);
        qa[dc][6] = (short)f2bf(f1.z); qa[dc][7] = (short)f2bf(f1.w);
    }

    f32x4 o[4];
#pragma unroll
    for (int nt = 0; nt < 4; ++nt) { o[nt][0]=0.f; o[nt][1]=0.f; o[nt][2]=0.f; o[nt][3]=0.f; }
    float m_r[4] = {-1e30f, -1e30f, -1e30f, -1e30f};
    float l_r[4] = {0.f, 0.f, 0.f, 0.f};

    const float* kbase = K + ((size_t)b * NH + h) * NKV * DH;
    const float* vbase = V + ((size_t)b * NH + h) * NKV * DH;
    const float* mrow[4];
#pragma unroll
    for (int r = 0; r < 4; ++r)
        mrow[r] = M + (size_t)b * NQ * NKV + (size_t)(q0 + wv * 16 + g * 4 + r) * NKV + l16;

    const int r0 = tid >> 4, c0 = (tid & 15) * 4;

    float4 kr[4], vr[4];
    float  mr[4][4];
#pragma unroll
    for (int i = 0; i < 4; ++i) {
        kr[i] = *(const float4*)(kbase + (size_t)(i * 16 + r0) * DH + c0);
        vr[i] = *(const float4*)(vbase + (size_t)(i * 16 + r0) * DH + c0);
    }
#pragma unroll
    for (int r = 0; r < 4; ++r)
#pragma unroll
        for (int nt = 0; nt < 4; ++nt) mr[r][nt] = mrow[r][nt * 16];

    for (int t = 0; t < NKV / 64; ++t) {
        const int kv0 = t * 64;
        const int kvn = ((t + 1) & 31) * 64;

        __syncthreads();
#pragma unroll
        for (int i = 0; i < 4; ++i) {
            unsigned short* dst = &Ks[i * 16 + r0][c0];
            dst[0] = f2bf(kr[i].x); dst[1] = f2bf(kr[i].y);
            dst[2] = f2bf(kr[i].z); dst[3] = f2bf(kr[i].w);
        }
#pragma unroll
        for (int i = 0; i < 4; ++i) {
            const int rr = i * 16 + r0;
            Vs[c0 + 0][rr] = f2bf(vr[i].x); Vs[c0 + 1][rr] = f2bf(vr[i].y);
            Vs[c0 + 2][rr] = f2bf(vr[i].z); Vs[c0 + 3][rr] = f2bf(vr[i].w);
        }
#pragma unroll
        for (int i = 0; i < 4; ++i) {
            kr[i] = *(const float4*)(kbase + (size_t)(kvn + i * 16 + r0) * DH + c0);
            vr[i] = *(const float4*)(vbase + (size_t)(kvn + i * 16 + r0) * DH + c0);
        }
        __syncthreads();

        f32x4 s[4];
#pragma unroll
        for (int nt = 0; nt < 4; ++nt) {
            f32x4 acc; acc[0]=0.f; acc[1]=0.f; acc[2]=0.f; acc[3]=0.f;
            const bf16x8 kb0 = *(const bf16x8*)(&Ks[nt * 16 + l16][g * 8]);
            const bf16x8 kb1 = *(const bf16x8*)(&Ks[nt * 16 + l16][32 + g * 8]);
            acc = __builtin_amdgcn_mfma_f32_16x16x32_bf16(qa[0], kb0, acc, 0, 0, 0);
            acc = __builtin_amdgcn_mfma_f32_16x16x32_bf16(qa[1], kb1, acc, 0, 0, 0);
            s[nt] = acc;
        }

#pragma unroll
        for (int r = 0; r < 4; ++r) {
            const int qr = wv * 16 + g * 4 + r;
#pragma unroll
            for (int nt = 0; nt < 4; ++nt) {
                float x = s[nt][r] * 0.125f + mr[r][nt];
                x += bias_s[qr - (kv0 + nt * 16 + l16) + 2047];
                s[nt][r] = x;
            }
            float mx = fmaxf(fmaxf(s[0][r], s[1][r]), fmaxf(s[2][r], s[3][r]));
            mx = fmaxf(mx, __shfl_xor(mx, 1));
            mx = fmaxf(mx, __shfl_xor(mx, 2));
            mx = fmaxf(mx, __shfl_xor(mx, 4));
            mx = fmaxf(mx, __shfl_xor(mx, 8));
            const float mo = m_r[r];
            const float mn = fmaxf(mo, mx);
            m_r[r] = mn;
            const float alpha = __expf(mo - mn);
            float p[4], rs = 0.f;
#pragma unroll
            for (int nt = 0; nt < 4; ++nt) { p[nt] = __expf(s[nt][r] - mn); rs += p[nt]; }
            rs += __shfl_xor(rs, 1);
            rs += __shfl_xor(rs, 2);
            rs += __shfl_xor(rs, 4);
            rs += __shfl_xor(rs, 8);
            l_r[r] = l_r[r] * alpha + rs;
#pragma unroll
            for (int nt = 0; nt < 4; ++nt) o[nt][r] *= alpha;
#pragma unroll
            for (int nt = 0; nt < 4; ++nt)
                Ps[wv][g * 4 + r][nt * 16 + l16] = f2bf(p[nt]);
        }

#pragma unroll
        for (int r = 0; r < 4; ++r)
#pragma unroll
            for (int nt = 0; nt < 4; ++nt) mr[r][nt] = mrow[r][kvn + nt * 16];

#pragma unroll
        for (int kc = 0; kc < 2; ++kc) {
            const bf16x8 pa = *(const bf16x8*)(&Ps[wv][l16][kc * 32 + g * 8]);
#pragma unroll
            for (int nt = 0; nt < 4; ++nt) {
                const bf16x8 vb = *(const bf16x8*)(&Vs[nt * 16 + l16][kc * 32 + g * 8]);
                o[nt] = __builtin_amdgcn_mfma_f32_16x16x32_bf16(pa, vb, o[nt], 0, 0, 0);
            }
        }
    }

    float* obase = O + (((size_t)b * NH + h) * NQ + q0 + wv * 16) * DH;
#pragma unroll
    for (int r = 0; r < 4; ++r) {
        const float inv = 1.f / l_r[r];
#pragma unroll
        for (int nt = 0; nt < 4; ++nt)
            obase[(size_t)(g * 4 + r) * DH + nt * 16 + l16] = o[nt][r] * inv;
    }
}

extern "C" void kernel_launch(void* const* d_in, const int* in_sizes, int n_in,
                              void* d_out, int out_size, void* d_ws, size_t ws_size,
                              hipStream_t stream) {
    const float* Q    = (const float*)d_in[0];
    const float* K    = (const float*)d_in[1];
    const float* V    = (const float*)d_in[2];
    const float* M    = (const float*)d_in[3];
    const float* Bias = (const float*)d_in[4];
    float* O = (float*)d_out;

    if (ws_size >= (size_t)WS_NEED) {
        unsigned short* Kb = (unsigned short*)((char*)d_ws + WS_KB);
        unsigned short* Vt = (unsigned short*)((char*)d_ws + WS_VT);
        float* Op = (float*)((char*)d_ws + WS_OP);
        float* Ml = (float*)((char*)d_ws + WS_ML);
        conv_kv<<<dim3(BH * 32), dim3(256), 0, stream>>>(K, V, Kb, Vt);
        attn_split<<<dim3(BH * 64), dim3(256), 0, stream>>>(Kb, Vt, Q, M, Bias, Op, Ml);
        attn_merge<<<dim3((int)(OPHALF / 4 / 256)), dim3(256), 0, stream>>>(Op, Ml, O);
    } else {
        attn_full<<<dim3(BH * 32), dim3(256), 0, stream>>>(Q, K, V, M, Bias, O);
    }
}

// Round 7
// 143.249 us; speedup vs baseline: 2.4433x; 1.9427x over previous
//
#include <hip/hip_runtime.h>

#define NB  2
#define NH  12
#define NQ  2048
#define NKV 2048
#define DH  64
#define KVB 64
#define BH  (NB * NH)

#define L2E 1.44269504088896f
#define QSCL (0.125f * L2E)

typedef __attribute__((ext_vector_type(8))) short bf16x8;
typedef __attribute__((ext_vector_type(4))) float f32x4;

#define EXP2F(x) __builtin_amdgcn_exp2f(x)

// workspace: Kb bf16[bh][kv][d] | Vt bf16[bh][d][kv]
#define WS_KB   0u
#define WS_VT   6291456u
#define WS_NEED 12582912u

__device__ __forceinline__ unsigned short f2bf(float f) {
    unsigned int u = __float_as_uint(f);
    u += 0x7FFFu + ((u >> 16) & 1u);          // round-to-nearest-even
    return (unsigned short)(u >> 16);
}

// ============ pass 1: K -> bf16 copy, V -> bf16 transpose (proven in R5) ============
__global__ __launch_bounds__(256)
void conv_kv(const float* __restrict__ K, const float* __restrict__ V,
             unsigned short* __restrict__ Kb, unsigned short* __restrict__ Vt)
{
    const int tid = threadIdx.x;
    const int kvt = blockIdx.x & 31;
    const int bh  = blockIdx.x >> 5;
    const int kv0 = kvt * 64;

    const float* ksrc = K + ((size_t)bh * NKV + kv0) * DH;
    const float* vsrc = V + ((size_t)bh * NKV + kv0) * DH;
    unsigned short* kdst = Kb + ((size_t)bh * NKV + kv0) * DH;
    unsigned short* vdst = Vt + (size_t)bh * DH * NKV + kv0;

    __shared__ float Ts[64][65];

#pragma unroll
    for (int p = 0; p < 2; ++p) {
        const int ch = p * 256 + tid;
        const int row = ch >> 3, c8 = (ch & 7) * 8;
        const float4 f0 = *(const float4*)(ksrc + (size_t)row * DH + c8);
        const float4 f1 = *(const float4*)(ksrc + (size_t)row * DH + c8 + 4);
        bf16x8 o;
        o[0] = (short)f2bf(f0.x); o[1] = (short)f2bf(f0.y);
        o[2] = (short)f2bf(f0.z); o[3] = (short)f2bf(f0.w);
        o[4] = (short)f2bf(f1.x); o[5] = (short)f2bf(f1.y);
        o[6] = (short)f2bf(f1.z); o[7] = (short)f2bf(f1.w);
        *(bf16x8*)(kdst + (size_t)row * DH + c8) = o;
    }
#pragma unroll
    for (int p = 0; p < 4; ++p) {
        const int fi = p * 1024 + tid * 4;
        const int row = fi >> 6, col = fi & 63;
        const float4 f = *(const float4*)(vsrc + (size_t)row * DH + col);
        Ts[row][col] = f.x; Ts[row][col + 1] = f.y;
        Ts[row][col + 2] = f.z; Ts[row][col + 3] = f.w;
    }
    __syncthreads();
#pragma unroll
    for (int p = 0; p < 2; ++p) {
        const int ch = p * 256 + tid;
        const int d = ch >> 3, c8 = (ch & 7) * 8;
        bf16x8 o;
#pragma unroll
        for (int j = 0; j < 8; ++j) o[j] = (short)f2bf(Ts[c8 + j][d]);
        *(bf16x8*)(vdst + (size_t)d * NKV + c8) = o;
    }
}

// ============ pass 2: flash attention, 8 waves = 4 q-subtiles x 2 kv-halves ============
// LDS arena (bytes):
//   [0,     8448)  bias_s f32[2112] (pre-scaled by log2e)
//   [8448, 17664)  Ks u16[64][72]          | merge: mO f32[4][16][68] (17408 B)
//   [17664,26880)  Vs u16[64][72]          |        mML f32[128] at 25856
//   [26880,37120)  Ps u16[8][16][40]
#define ARENA_BYTES 37120

__global__ __launch_bounds__(512, 2)
void attn_fwd(const unsigned short* __restrict__ Kb, const unsigned short* __restrict__ Vt,
              const float* __restrict__ Q, const float* __restrict__ M,
              const float* __restrict__ Bias, float* __restrict__ O)
{
    const int tid  = threadIdx.x;
    const int w    = tid >> 6;      // wave 0..7
    const int wq   = w >> 1;        // q-subtile: rows [wq*16, wq*16+16)
    const int wk   = w & 1;         // kv-half: cols [wk*32, wk*32+32) of each 64-tile
    const int lane = tid & 63;
    const int l16  = lane & 15;
    const int g    = lane >> 4;

    const int qt = blockIdx.x & 31;
    const int bh = blockIdx.x >> 5;
    const int h  = bh % NH;
    const int b  = bh / NH;
    const int q0 = qt * 64;

    __shared__ __align__(16) char arena[ARENA_BYTES];
    float* bias_s                = (float*)arena;
    unsigned short (*Ks)[72]     = (unsigned short(*)[72])(arena + 8448);
    unsigned short (*Vs)[72]     = (unsigned short(*)[72])(arena + 17664);
    unsigned short (*Ps)[16][40] = (unsigned short(*)[16][40])(arena + 26880);

    // bias band (pre-scaled by log2e): bias_s[i] = L2E * Bias[(q0+1+i)*NH + h]
    for (int i = tid; i < 2112; i += 512)
        bias_s[i] = L2E * Bias[(size_t)(q0 + 1 + i) * NH + h];

    // Q fragments pre-scaled by 0.125*log2e (A-frag: row=l16, k=g*8+j)
    const float* qptr = Q + ((size_t)bh * NQ + q0 + wq * 16 + l16) * DH;
    bf16x8 qa[2];
#pragma unroll
    for (int dc = 0; dc < 2; ++dc) {
        const float4 f0 = *(const float4*)(qptr + dc * 32 + g * 8);
        const float4 f1 = *(const float4*)(qptr + dc * 32 + g * 8 + 4);
        qa[dc][0] = (short)f2bf(f0.x * QSCL); qa[dc][1] = (short)f2bf(f0.y * QSCL);
        qa[dc][2] = (short)f2bf(f0.z * QSCL); qa[dc][3] = (short)f2bf(f0.w * QSCL);
        qa[dc][4] = (short)f2bf(f1.x * QSCL); qa[dc][5] = (short)f2bf(f1.y * QSCL);
        qa[dc][6] = (short)f2bf(f1.z * QSCL); qa[dc][7] = (short)f2bf(f1.w * QSCL);
    }

    f32x4 o[4];
#pragma unroll
    for (int nt = 0; nt < 4; ++nt) { o[nt][0]=0.f; o[nt][1]=0.f; o[nt][2]=0.f; o[nt][3]=0.f; }
    float m_r[4] = {-1e30f, -1e30f, -1e30f, -1e30f};
    float l_r[4] = {0.f, 0.f, 0.f, 0.f};

    const unsigned short* kbB = Kb + (size_t)bh * NKV * DH;
    const unsigned short* vtB = Vt + (size_t)bh * DH * NKV;
    const float* mbase = M + (size_t)b * NQ * NKV
                           + (size_t)(q0 + wq * 16 + g * 4) * NKV + wk * 32 + l16;

    // staging: 512 threads cover 64 rows x 64 cols (one bf16x8 each for K and Vt)
    const int srow = tid >> 3, sc8 = (tid & 7) * 8;

    // prologue: tile-0 loads
    bf16x8 krB, vrB;
    float  mr[4][2];
    krB = *(const bf16x8*)(kbB + (size_t)srow * DH + sc8);
    vrB = *(const bf16x8*)(vtB + (size_t)srow * NKV + sc8);
#pragma unroll
    for (int r = 0; r < 4; ++r)
#pragma unroll
        for (int nt = 0; nt < 2; ++nt) mr[r][nt] = mbase[(size_t)r * NKV + nt * 16];

    for (int t = 0; t < NKV / KVB; ++t) {
        const int kv0 = t * KVB;
        const int tn  = ((t + 1) & (NKV / KVB - 1)) * KVB;

        __syncthreads();
        *(bf16x8*)(&Ks[srow][sc8]) = krB;
        *(bf16x8*)(&Vs[srow][sc8]) = vrB;
        krB = *(const bf16x8*)(kbB + (size_t)(tn + srow) * DH + sc8);
        vrB = *(const bf16x8*)(vtB + (size_t)srow * NKV + tn + sc8);
        __syncthreads();

        // S' = (Q*qscl) K^T  (already in log2 domain) for this wave's 16q x 32kv
        f32x4 s[2];
#pragma unroll
        for (int nt = 0; nt < 2; ++nt) {
            f32x4 acc; acc[0]=0.f; acc[1]=0.f; acc[2]=0.f; acc[3]=0.f;
            const int kvrow = wk * 32 + nt * 16 + l16;
            const bf16x8 kb0 = *(const bf16x8*)(&Ks[kvrow][g * 8]);
            const bf16x8 kb1 = *(const bf16x8*)(&Ks[kvrow][32 + g * 8]);
            acc = __builtin_amdgcn_mfma_f32_16x16x32_bf16(qa[0], kb0, acc, 0, 0, 0);
            acc = __builtin_amdgcn_mfma_f32_16x16x32_bf16(qa[1], kb1, acc, 0, 0, 0);
            s[nt] = acc;
        }

        // bias + mask (log2 domain), online softmax with defer-max
#pragma unroll
        for (int r = 0; r < 4; ++r) {
            const int qr = wq * 16 + g * 4 + r;
#pragma unroll
            for (int nt = 0; nt < 2; ++nt) {
                const int kk = kv0 + wk * 32 + nt * 16 + l16;
                s[nt][r] += __fmaf_rn(mr[r][nt], L2E, bias_s[qr - kk + 2047]);
            }
            float mx = fmaxf(s[0][r], s[1][r]);
            mx = fmaxf(mx, __shfl_xor(mx, 1));
            mx = fmaxf(mx, __shfl_xor(mx, 2));
            mx = fmaxf(mx, __shfl_xor(mx, 4));
            mx = fmaxf(mx, __shfl_xor(mx, 8));
            const float mo = m_r[r];
            if (__any(mx > mo + 8.0f)) {        // wave-uniform rescale (rare after tile 0)
                const float mn = fmaxf(mo, mx);
                const float alpha = EXP2F(mo - mn);
                m_r[r] = mn;
                l_r[r] *= alpha;
#pragma unroll
                for (int nt = 0; nt < 4; ++nt) o[nt][r] *= alpha;
            }
            const float mn = m_r[r];
            const float p0 = EXP2F(s[0][r] - mn);
            const float p1 = EXP2F(s[1][r] - mn);
            float rs = p0 + p1;
            rs += __shfl_xor(rs, 1);
            rs += __shfl_xor(rs, 2);
            rs += __shfl_xor(rs, 4);
            rs += __shfl_xor(rs, 8);
            l_r[r] += rs;
            Ps[w][g * 4 + r][l16]      = f2bf(p0);
            Ps[w][g * 4 + r][16 + l16] = f2bf(p1);
        }

        // prefetch next-tile mask
#pragma unroll
        for (int r = 0; r < 4; ++r)
#pragma unroll
            for (int nt = 0; nt < 2; ++nt) mr[r][nt] = mbase[(size_t)r * NKV + tn + nt * 16];

        // PV: A = P (16x32 slice), B^T = V^T rows, kv cols wk*32 + g*8
        const bf16x8 pa = *(const bf16x8*)(&Ps[w][l16][g * 8]);
#pragma unroll
        for (int nt = 0; nt < 4; ++nt) {
            const bf16x8 vb = *(const bf16x8*)(&Vs[nt * 16 + l16][wk * 32 + g * 8]);
            o[nt] = __builtin_amdgcn_mfma_f32_16x16x32_bf16(pa, vb, o[nt], 0, 0, 0);
        }
    }

    // ==== merge the two kv-halves (wk=0 <- wk=1) through LDS ====
    __syncthreads();
    float (*mO)[16][68] = (float(*)[16][68])(arena + 8448);
    float* mML          = (float*)(arena + 25856);          // m[64] | l[64]

    if (wk == 1) {
#pragma unroll
        for (int r = 0; r < 4; ++r) {
#pragma unroll
            for (int nt = 0; nt < 4; ++nt)
                mO[wq][g * 4 + r][nt * 16 + l16] = o[nt][r];
            if (l16 == 0) {
                mML[wq * 16 + g * 4 + r]      = m_r[r];
                mML[64 + wq * 16 + g * 4 + r] = l_r[r];
            }
        }
    }
    __syncthreads();
    if (wk == 0) {
        float* obase = O + ((size_t)bh * NQ + q0 + wq * 16) * DH;
#pragma unroll
        for (int r = 0; r < 4; ++r) {
            const int row = g * 4 + r;
            const float m1 = mML[wq * 16 + row];
            const float l1 = mML[64 + wq * 16 + row];
            const float mn = fmaxf(m_r[r], m1);
            const float a0 = EXP2F(m_r[r] - mn);
            const float a1 = EXP2F(m1 - mn);
            const float inv = 1.f / (l_r[r] * a0 + l1 * a1);
#pragma unroll
            for (int nt = 0; nt < 4; ++nt)
                obase[(size_t)row * DH + nt * 16 + l16] =
                    (o[nt][r] * a0 + mO[wq][row][nt * 16 + l16] * a1) * inv;
        }
    }
}

// ============ fallback: R2 kernel (known-good, 147 us) ============
__global__ __launch_bounds__(256, 3)
void attn_full(const float* __restrict__ Q, const float* __restrict__ K,
               const float* __restrict__ V, const float* __restrict__ M,
               const float* __restrict__ Bias, float* __restrict__ O)
{
    const int tid  = threadIdx.x;
    const int wv   = tid >> 6;
    const int lane = tid & 63;
    const int l16  = lane & 15;
    const int g    = lane >> 4;

    const int qt = blockIdx.x & 31;
    const int h  = (blockIdx.x >> 5) % NH;
    const int b  = blockIdx.x / (32 * NH);
    const int q0 = qt * 64;

    __shared__ float bias_s[2112];
    __shared__ unsigned short Ks[64][72];
    __shared__ unsigned short Vs[64][72];
    __shared__ unsigned short Ps[4][16][72];

    for (int i = tid; i < 2112; i += 256)
        bias_s[i] = Bias[(size_t)(q0 + 1 + i) * NH + h];

    const float* qptr = Q + (((size_t)b * NH + h) * NQ + q0 + wv * 16 + l16) * DH;
    bf16x8 qa[2];
#pragma unroll
    for (int dc = 0; dc < 2; ++dc) {
        const float4 f0 = *(const float4*)(qptr + dc * 32 + g * 8);
        const float4 f1 = *(const float4*)(qptr + dc * 32 + g * 8 + 4);
        qa[dc][0] = (short)f2bf(f0.x); qa[dc][1] = (short)f2bf(f0.y);
        qa[dc][2] = (short)f2bf(f0.z); qa[dc][3] = (short)f2bf(f0.w);
        qa[dc][4] = (short)f2bf(f1.x); qa[dc][5] = (short)f2bf(f1.y);
        qa[dc][6] = (short)f2bf(f1.z); qa[dc][7] = (short)f2bf(f1.w);
    }

    f32x4 o[4];
#pragma unroll
    for (int nt = 0; nt < 4; ++nt) { o[nt][0]=0.f; o[nt][1]=0.f; o[nt][2]=0.f; o[nt][3]=0.f; }
    float m_r[4] = {-1e30f, -1e30f, -1e30f, -1e30f};
    float l_r[4] = {0.f, 0.f, 0.f, 0.f};

    const float* kbase = K + ((size_t)b * NH + h) * NKV * DH;
    const float* vbase = V + ((size_t)b * NH + h) * NKV * DH;
    const float* mrow[4];
#pragma unroll
    for (int r = 0; r < 4; ++r)
        mrow[r] = M + (size_t)b * NQ * NKV + (size_t)(q0 + wv * 16 + g * 4 + r) * NKV + l16;

    const int r0 = tid >> 4, c0 = (tid & 15) * 4;

    float4 kr[4], vr[4];
    float  mr[4][4];
#pragma unroll
    for (int i = 0; i < 4; ++i) {
        kr[i] = *(const float4*)(kbase + (size_t)(i * 16 + r0) * DH + c0);
        vr[i] = *(const float4*)(vbase + (size_t)(i * 16 + r0) * DH + c0);
    }
#pragma unroll
    for (int r = 0; r < 4; ++r)
#pragma unroll
        for (int nt = 0; nt < 4; ++nt) mr[r][nt] = mrow[r][nt * 16];

    for (int t = 0; t < NKV / 64; ++t) {
        const int kv0 = t * 64;
        const int kvn = ((t + 1) & 31) * 64;

        __syncthreads();
#pragma unroll
        for (int i = 0; i < 4; ++i) {
            unsigned short* dst = &Ks[i * 16 + r0][c0];
            dst[0] = f2bf(kr[i].x); dst[1] = f2bf(kr[i].y);
            dst[2] = f2bf(kr[i].z); dst[3] = f2bf(kr[i].w);
        }
#pragma unroll
        for (int i = 0; i < 4; ++i) {
            const int rr = i * 16 + r0;
            Vs[c0 + 0][rr] = f2bf(vr[i].x); Vs[c0 + 1][rr] = f2bf(vr[i].y);
            Vs[c0 + 2][rr] = f2bf(vr[i].z); Vs[c0 + 3][rr] = f2bf(vr[i].w);
        }
#pragma unroll
        for (int i = 0; i < 4; ++i) {
            kr[i] = *(const float4*)(kbase + (size_t)(kvn + i * 16 + r0) * DH + c0);
            vr[i] = *(const float4*)(vbase + (size_t)(kvn + i * 16 + r0) * DH + c0);
        }
        __syncthreads();

        f32x4 s[4];
#pragma unroll
        for (int nt = 0; nt < 4; ++nt) {
            f32x4 acc; acc[0]=0.f; acc[1]=0.f; acc[2]=0.f; acc[3]=0.f;
            const bf16x8 kb0 = *(const bf16x8*)(&Ks[nt * 16 + l16][g * 8]);
            const bf16x8 kb1 = *(const bf16x8*)(&Ks[nt * 16 + l16][32 + g * 8]);
            acc = __builtin_amdgcn_mfma_f32_16x16x32_bf16(qa[0], kb0, acc, 0, 0, 0);
            acc = __builtin_amdgcn_mfma_f32_16x16x32_bf16(qa[1], kb1, acc, 0, 0, 0);
            s[nt] = acc;
        }

#pragma unroll
        for (int r = 0; r < 4; ++r) {
            const int qr = wv * 16 + g * 4 + r;
#pragma unroll
            for (int nt = 0; nt < 4; ++nt) {
                float x = s[nt][r] * 0.125f + mr[r][nt];
                x += bias_s[qr - (kv0 + nt * 16 + l16) + 2047];
                s[nt][r] = x;
            }
            float mx = fmaxf(fmaxf(s[0][r], s[1][r]), fmaxf(s[2][r], s[3][r]));
            mx = fmaxf(mx, __shfl_xor(mx, 1));
            mx = fmaxf(mx, __shfl_xor(mx, 2));
            mx = fmaxf(mx, __shfl_xor(mx, 4));
            mx = fmaxf(mx, __shfl_xor(mx, 8));
            const float mo = m_r[r];
            const float mn = fmaxf(mo, mx);
            m_r[r] = mn;
            const float alpha = __expf(mo - mn);
            float p[4], rs = 0.f;
#pragma unroll
            for (int nt = 0; nt < 4; ++nt) { p[nt] = __expf(s[nt][r] - mn); rs += p[nt]; }
            rs += __shfl_xor(rs, 1);
            rs += __shfl_xor(rs, 2);
            rs += __shfl_xor(rs, 4);
            rs += __shfl_xor(rs, 8);
            l_r[r] = l_r[r] * alpha + rs;
#pragma unroll
            for (int nt = 0; nt < 4; ++nt) o[nt][r] *= alpha;
#pragma unroll
            for (int nt = 0; nt < 4; ++nt)
                Ps[wv][g * 4 + r][nt * 16 + l16] = f2bf(p[nt]);
        }

#pragma unroll
        for (int r = 0; r < 4; ++r)
#pragma unroll
            for (int nt = 0; nt < 4; ++nt) mr[r][nt] = mrow[r][kvn + nt * 16];

#pragma unroll
        for (int kc = 0; kc < 2; ++kc) {
            const bf16x8 pa = *(const bf16x8*)(&Ps[wv][l16][kc * 32 + g * 8]);
#pragma unroll
            for (int nt = 0; nt < 4; ++nt) {
                const bf16x8 vb = *(const bf16x8*)(&Vs[nt * 16 + l16][kc * 32 + g * 8]);
                o[nt] = __builtin_amdgcn_mfma_f32_16x16x32_bf16(pa, vb, o[nt], 0, 0, 0);
            }
        }
    }

    float* obase = O + (((size_t)b * NH + h) * NQ + q0 + wv * 16) * DH;
#pragma unroll
    for (int r = 0; r < 4; ++r) {
        const float inv = 1.f / l_r[r];
#pragma unroll
        for (int nt = 0; nt < 4; ++nt)
            obase[(size_t)(g * 4 + r) * DH + nt * 16 + l16] = o[nt][r] * inv;
    }
}

extern "C" void kernel_launch(void* const* d_in, const int* in_sizes, int n_in,
                              void* d_out, int out_size, void* d_ws, size_t ws_size,
                              hipStream_t stream) {
    const float* Q    = (const float*)d_in[0];
    const float* K    = (const float*)d_in[1];
    const float* V    = (const float*)d_in[2];
    const float* M    = (const float*)d_in[3];
    const float* Bias = (const float*)d_in[4];
    float* O = (float*)d_out;

    if (ws_size >= (size_t)WS_NEED) {
        unsigned short* Kb = (unsigned short*)((char*)d_ws + WS_KB);
        unsigned short* Vt = (unsigned short*)((char*)d_ws + WS_VT);
        conv_kv<<<dim3(BH * 32), dim3(256), 0, stream>>>(K, V, Kb, Vt);
        attn_fwd<<<dim3(BH * 32), dim3(512), 0, stream>>>(Kb, Vt, Q, M, Bias, O);
    } else {
        attn_full<<<dim3(BH * 32), dim3(256), 0, stream>>>(Q, K, V, M, Bias, O);
    }
}